// Round 14
// baseline (427.224 us; speedup 1.0000x reference)
//
#include <hip/hip_runtime.h>
#include <hip/hip_bf16.h>

#define N_NODES 50000
#define N_EDGES 800000
#define F 256
#define NGRAPH 64
#define NCLS 16
#define NBLK_N 196   // ceil(50000/256)

typedef short short8 __attribute__((ext_vector_type(8)));
typedef float f32x4 __attribute__((ext_vector_type(4)));

__device__ __forceinline__ float bf2f(ushort u) {
    unsigned v = ((unsigned)u) << 16;
    return __uint_as_float(v);
}
__device__ __forceinline__ ushort f2bf(float f) {
    __hip_bfloat16 b = __float2bfloat16(f);   // RNE
    return *reinterpret_cast<ushort*>(&b);
}
__device__ __forceinline__ float bflo(uint u) { return __uint_as_float(u << 16); }
__device__ __forceinline__ float bfhi(uint u) { return __uint_as_float(u & 0xffff0000u); }

// ---------------- init (zeroed buffers, fused) ----------------

__global__ __launch_bounds__(256) void k_init(int* __restrict__ ecnt,
                                              float* __restrict__ pool,
                                              float* __restrict__ cnt) {
    int i = blockIdx.x * 256 + threadIdx.x;
    if (i < N_NODES) ecnt[i] = 0;
    if (i < NGRAPH * NCLS) pool[i] = 0.f;
    if (i < NGRAPH) cnt[i] = 0.f;
}

__global__ __launch_bounds__(256) void k_count(const int* __restrict__ dst,
                                               int* __restrict__ ecnt) {
    int e = blockIdx.x * 256 + threadIdx.x;
    if (e < N_EDGES) atomicAdd(&ecnt[dst[e]], 1);
}

// block-scan over ecnt; also emits dinv and sdeg (fused)
__global__ __launch_bounds__(256) void k_scan_block(const int* __restrict__ ecnt,
                                                    int* __restrict__ rowptr,
                                                    int* __restrict__ blkSum,
                                                    float* __restrict__ dinv,
                                                    float* __restrict__ sdeg) {
    __shared__ int sh[256];
    int i = blockIdx.x * 256 + threadIdx.x;
    int v = (i < N_NODES) ? ecnt[i] : 0;
    sh[threadIdx.x] = v;
    __syncthreads();
#pragma unroll
    for (int off = 1; off < 256; off <<= 1) {
        int t = (threadIdx.x >= off) ? sh[threadIdx.x - off] : 0;
        __syncthreads();
        sh[threadIdx.x] += t;
        __syncthreads();
    }
    if (i < N_NODES) {
        rowptr[i] = sh[threadIdx.x] - v;
        float d = (float)(v + 1);
        dinv[i] = rsqrtf(d);        // +1 self-loop
        sdeg[i] = sqrtf(d);
    }
    if (threadIdx.x == 255) blkSum[blockIdx.x] = sh[255];
}

// per-block: reduce blkSum[0..bid) inline, add.
__global__ __launch_bounds__(256) void k_scan_add(const int* __restrict__ blkSum,
                                                  int* __restrict__ rowptr,
                                                  int* __restrict__ cursor) {
    __shared__ int sh[256];
    int t = threadIdx.x;
    sh[t] = (t < NBLK_N && t < (int)blockIdx.x) ? blkSum[t] : 0;
    __syncthreads();
#pragma unroll
    for (int off = 128; off > 0; off >>= 1) {
        if (t < off) sh[t] += sh[t + off];
        __syncthreads();
    }
    int base = sh[0];
    int i = blockIdx.x * 256 + t;
    if (i < N_NODES) {
        int r = rowptr[i] + base;
        rowptr[i] = r;
        cursor[i] = r;
    }
    if (i == 0) rowptr[N_NODES] = N_EDGES;
}

__global__ __launch_bounds__(256) void k_fill_csr(const int* __restrict__ src,
                                                  const int* __restrict__ dst,
                                                  int* __restrict__ cursor,
                                                  ushort* __restrict__ csr16) {
    int e = blockIdx.x * 256 + threadIdx.x;
    if (e >= N_EDGES) return;
    int s = src[e];
    int d = dst[e];
    int p = atomicAdd(&cursor[d], 1);
    csr16[p] = (ushort)s;
}

// ---------------- prescale: T0 = bf16( x * dinv[row] ) ----------------

__global__ __launch_bounds__(256) void k_prescale(const float* __restrict__ x,
                                                  const float* __restrict__ dinv,
                                                  ushort* __restrict__ T0) {
    int i = blockIdx.x * 256 + threadIdx.x;    // short8 group index
    if (i >= (int)((size_t)N_NODES * F / 8)) return;
    int n = i >> 5;                            // 32 groups per 256-row
    float di = dinv[n];
    const float4* ip = (const float4*)(x + (size_t)i * 8);
    float4 a = ip[0], b = ip[1];
    short8 v;
    v[0] = (short)f2bf(a.x * di); v[1] = (short)f2bf(a.y * di);
    v[2] = (short)f2bf(a.z * di); v[3] = (short)f2bf(a.w * di);
    v[4] = (short)f2bf(b.x * di); v[5] = (short)f2bf(b.y * di);
    v[6] = (short)f2bf(b.z * di); v[7] = (short)f2bf(b.w * di);
    *(short8*)(T0 + (size_t)i * 8) = v;
}

// ---------------- weight pack: all three 256x256 in one launch ----------------

__global__ __launch_bounds__(256) void k_wpack3(const float* __restrict__ W1,
                                                const float* __restrict__ W2,
                                                const float* __restrict__ W3,
                                                ushort* __restrict__ Wp) {
    int gid = blockIdx.x * 256 + threadIdx.x;
    int which = gid >> 13;          // 8192 frag-groups per matrix
    int idx = gid & 8191;
    const float* W = (which == 0) ? W1 : (which == 1) ? W2 : W3;
    ushort* o = Wp + (size_t)which * 65536;
    int lane = idx & 63;
    int ks = (idx >> 6) & 7;
    int ctg = idx >> 9;
    int kbase = ks * 32 + (lane >> 4) * 8;
    int col = ctg * 16 + (lane & 15);
    short8 v;
#pragma unroll
    for (int e = 0; e < 8; ++e)
        v[e] = (short)f2bf(W[(size_t)(kbase + e) * 256 + col]);
    *(short8*)(o + (size_t)idx * 8) = v;
}

// ---------------- fused layer: OUT = dinv * act( (A_hat Hs_unscaled) W + b ) ----------
// Uses commutation A_hat(HW) = (A_hat H)W.
// Hs is the dinv-PRESCALED prev activation table (bf16). Per 32-node block:
//   Phase A: gather agg[d] = dinv_d * (sum_{s in N(d)} Hs[s] + Hs[d]) -> LDS A-tile
//   Phase B: (A-tile) @ W via MFMA, wf[8] streamed per ct (low VGPR)
//   Phase C: z -> relu(z+b) [MODE2: -> relu(. + Hs[d]*sdeg_d)] -> *dinv_d -> OUT
// MODE 1: relu(z+b)   MODE 2: relu(relu(z+b) + prev_unscaled)

template <int MODE>
__global__ __launch_bounds__(256) void k_layer(const ushort* __restrict__ Hs,
                                               const ushort* __restrict__ Wp,
                                               const float* __restrict__ bias,
                                               const float* __restrict__ dinv,
                                               const float* __restrict__ sdeg,
                                               const int* __restrict__ rowptr,
                                               const ushort* __restrict__ csr16,
                                               ushort* __restrict__ OUT) {
    __shared__ __align__(16) ushort At[32 * 264];     // agg A-tile, padded
    __shared__ __align__(16) ushort cs[4][16 * 72];   // per-wave C stage
    const int t = threadIdx.x;
    const int wv = t >> 6;
    const int l = t & 63;
    const int m0 = blockIdx.x * 32;

    // ---- Phase A: each wave gathers 8 nodes (2-slot: 32 lanes x 16B per row) ----
    {
        const int slot = l >> 5;
        const int c = (l & 31) * 8;
        for (int rep = 0; rep < 8; ++rep) {
            const int noderow = wv * 8 + rep;
            const int n = m0 + noderow;
            const bool valid = n < N_NODES;
            const int nn = valid ? n : 0;

            float acc[8];
#pragma unroll
            for (int j = 0; j < 8; ++j) acc[j] = 0.f;

            int i = valid ? rowptr[nn] + slot : 0;
            const int end = valid ? rowptr[nn + 1] : 0;
            for (; i + 6 < end; i += 8) {
                int s0 = csr16[i], s1 = csr16[i + 2], s2 = csr16[i + 4], s3 = csr16[i + 6];
                short8 v0 = *(const short8*)(Hs + (size_t)s0 * F + c);
                short8 v1 = *(const short8*)(Hs + (size_t)s1 * F + c);
                short8 v2 = *(const short8*)(Hs + (size_t)s2 * F + c);
                short8 v3 = *(const short8*)(Hs + (size_t)s3 * F + c);
#pragma unroll
                for (int j = 0; j < 8; ++j)
                    acc[j] += (bf2f((ushort)v0[j]) + bf2f((ushort)v1[j])) +
                              (bf2f((ushort)v2[j]) + bf2f((ushort)v3[j]));
            }
            for (; i < end; i += 2) {
                int s0 = csr16[i];
                short8 v0 = *(const short8*)(Hs + (size_t)s0 * F + c);
#pragma unroll
                for (int j = 0; j < 8; ++j) acc[j] += bf2f((ushort)v0[j]);
            }

#pragma unroll
            for (int j = 0; j < 8; ++j) acc[j] += __shfl_xor(acc[j], 32);

            if (slot == 0) {
                short8 av;
                if (valid) {
                    const short8 h = *(const short8*)(Hs + (size_t)nn * F + c);
                    float di = dinv[nn];
#pragma unroll
                    for (int j = 0; j < 8; ++j)
                        av[j] = (short)f2bf(di * (acc[j] + bf2f((ushort)h[j])));
                } else {
#pragma unroll
                    for (int j = 0; j < 8; ++j) av[j] = 0;
                }
                *(short8*)&At[noderow * 264 + c] = av;
            }
        }
    }
    __syncthreads();

    // ---- Phase B+C: MFMA on A-tile, epilogue, store ----
    const int colbase = wv * 64;
    const int lrow = l & 15;
    const int lk = (l >> 4) * 8;
    const short8* wp = (const short8*)Wp;

#pragma unroll
    for (int msub = 0; msub < 2; ++msub) {
        short8 af[8];
#pragma unroll
        for (int ks = 0; ks < 8; ++ks)
            af[ks] = *(const short8*)&At[(msub * 16 + lrow) * 264 + lk + ks * 32];

#pragma unroll
        for (int ct = 0; ct < 4; ++ct) {
            short8 wf[8];
#pragma unroll
            for (int ks = 0; ks < 8; ++ks)
                wf[ks] = wp[(size_t)(((wv * 4 + ct) * 8 + ks) * 64) + l];

            f32x4 acc = (f32x4){0.f, 0.f, 0.f, 0.f};
#pragma unroll
            for (int ks = 0; ks < 8; ++ks)
                acc = __builtin_amdgcn_mfma_f32_16x16x32_bf16(af[ks], wf[ks], acc, 0, 0, 0);

            int col = ct * 16 + (l & 15);
#pragma unroll
            for (int r = 0; r < 4; ++r) {
                int row = (l >> 4) * 4 + r;
                cs[wv][row * 72 + col] = f2bf(acc[r]);
            }
        }
        // readback + epilogue: 64 lanes cover 16 rows x 64 cols (2 passes)
#pragma unroll
        for (int h = 0; h < 2; ++h) {
            int row = h * 8 + (l >> 3);
            int coff = (l & 7) * 8;
            int orow = m0 + msub * 16 + row;
            if (orow < N_NODES) {
                short8 z8 = *(const short8*)&cs[wv][row * 72 + coff];
                int gcol = colbase + coff;
                const float4 b0 = *(const float4*)(bias + gcol);
                const float4 b1 = *(const float4*)(bias + gcol + 4);
                float bb[8] = {b0.x, b0.y, b0.z, b0.w, b1.x, b1.y, b1.z, b1.w};
                float di = dinv[orow];
                short8 ov;
                if (MODE == 2) {
                    const short8 hp = *(const short8*)(Hs + (size_t)orow * F + gcol);
                    float sd = sdeg[orow];
#pragma unroll
                    for (int j = 0; j < 8; ++j) {
                        float u = fmaxf(bf2f((ushort)z8[j]) + bb[j], 0.f);
                        u = fmaxf(u + bf2f((ushort)hp[j]) * sd, 0.f);
                        ov[j] = (short)f2bf(u * di);
                    }
                } else {
#pragma unroll
                    for (int j = 0; j < 8; ++j) {
                        float u = fmaxf(bf2f((ushort)z8[j]) + bb[j], 0.f);
                        ov[j] = (short)f2bf(u * di);
                    }
                }
                *(short8*)(OUT + (size_t)orow * F + gcol) = ov;
            }
        }
    }
}

// ---------------- layer 4: GEMM 256 -> 16 on PRESCALED table ----------------
// G16[r] = Hs3[r] @ W4   (dinv*sdeg = 1 makes this the prescaled h3W4 directly)

__global__ __launch_bounds__(256) void k_gemm16(const ushort* __restrict__ A,
                                                const float* __restrict__ W4,
                                                ushort* __restrict__ C) {
    __shared__ float Ws[256][16];
    const int t = threadIdx.x;
    {
        const float4* wp = (const float4*)(W4 + (size_t)t * 16);
        float4 a = wp[0], b = wp[1], c = wp[2], d = wp[3];
        float4* sp = (float4*)&Ws[t][0];
        sp[0] = a; sp[1] = b; sp[2] = c; sp[3] = d;
    }
    __syncthreads();
    int row = blockIdx.x * 256 + t;
    if (row >= N_NODES) return;
    const short8* ap = (const short8*)(A + (size_t)row * F);
    float acc[16];
#pragma unroll
    for (int c = 0; c < 16; ++c) acc[c] = 0.f;
    for (int k8 = 0; k8 < 32; ++k8) {
        short8 a8 = ap[k8];
#pragma unroll
        for (int j = 0; j < 8; ++j) {
            float av = bf2f((ushort)a8[j]);
            const float4* wr = (const float4*)&Ws[k8 * 8 + j][0];
            float4 w0 = wr[0], w1 = wr[1], w2 = wr[2], w3 = wr[3];
            acc[0]  += av * w0.x; acc[1]  += av * w0.y;
            acc[2]  += av * w0.z; acc[3]  += av * w0.w;
            acc[4]  += av * w1.x; acc[5]  += av * w1.y;
            acc[6]  += av * w1.z; acc[7]  += av * w1.w;
            acc[8]  += av * w2.x; acc[9]  += av * w2.y;
            acc[10] += av * w2.z; acc[11] += av * w2.w;
            acc[12] += av * w3.x; acc[13] += av * w3.y;
            acc[14] += av * w3.z; acc[15] += av * w3.w;
        }
    }
    short8 o0, o1;
#pragma unroll
    for (int c = 0; c < 8; ++c) o0[c] = (short)f2bf(acc[c]);
#pragma unroll
    for (int c = 0; c < 8; ++c) o1[c] = (short)f2bf(acc[8 + c]);
    short8* op = (short8*)(C + (size_t)row * 16);
    op[0] = o0; op[1] = o1;
}

// ---------------- fused layer-4 gather + mean-pool accumulate ----------------

__global__ __launch_bounds__(256) void k_g16pool(const ushort* __restrict__ G16,
                                                 const float* __restrict__ bias,
                                                 const float* __restrict__ dinv,
                                                 const int* __restrict__ rowptr,
                                                 const ushort* __restrict__ csr16,
                                                 const int* __restrict__ batch,
                                                 float* __restrict__ pool,
                                                 float* __restrict__ cnt) {
    __shared__ float ps[NGRAPH][NCLS];
    __shared__ float pc[NGRAPH];
    for (int i = threadIdx.x; i < NGRAPH * NCLS; i += 256) ((float*)ps)[i] = 0.f;
    if (threadIdx.x < NGRAPH) pc[threadIdx.x] = 0.f;
    __syncthreads();

    int gid = blockIdx.x * 256 + threadIdx.x;
    int n = gid >> 2;
    int q = (gid & 3) * 4;
    if (n < N_NODES) {
        float ax = 0.f, ay = 0.f, az = 0.f, aw = 0.f;
        const int end = rowptr[n + 1];
        for (int i = rowptr[n]; i < end; ++i) {
            int s0 = csr16[i];
            const uint2 u = *(const uint2*)(G16 + (size_t)s0 * 16 + q);
            ax += bflo(u.x); ay += bfhi(u.x);
            az += bflo(u.y); aw += bfhi(u.y);
        }
        const uint2 hu = *(const uint2*)(G16 + (size_t)n * 16 + q);
        const float4 b = *(const float4*)(bias + q);
        float di = dinv[n];
        int g = batch[n];
        atomicAdd(&ps[g][q + 0], b.x + di * (ax + bflo(hu.x)));
        atomicAdd(&ps[g][q + 1], b.y + di * (ay + bfhi(hu.x)));
        atomicAdd(&ps[g][q + 2], b.z + di * (az + bflo(hu.y)));
        atomicAdd(&ps[g][q + 3], b.w + di * (aw + bfhi(hu.y)));
        if ((gid & 3) == 0) atomicAdd(&pc[g], 1.f);
    }
    __syncthreads();

    for (int i = threadIdx.x; i < NGRAPH * NCLS; i += 256) {
        float v = ((float*)ps)[i];
        if (v != 0.f) unsafeAtomicAdd(&pool[i], v);
    }
    if (threadIdx.x < NGRAPH) {
        float v = pc[threadIdx.x];
        if (v > 0.f) unsafeAtomicAdd(&cnt[threadIdx.x], v);
    }
}

__global__ __launch_bounds__(256) void k_final(const float* __restrict__ pool,
                                               const float* __restrict__ cnt,
                                               float* __restrict__ out) {
    int i = blockIdx.x * 256 + threadIdx.x;
    if (i < NGRAPH * NCLS) out[i] = pool[i] / fmaxf(cnt[i >> 4], 1.f);
}

// ---------------- host ----------------

extern "C" void kernel_launch(void* const* d_in, const int* in_sizes, int n_in,
                              void* d_out, int out_size, void* d_ws, size_t ws_size,
                              hipStream_t stream) {
    const float* x   = (const float*)d_in[0];
    const int*   ei  = (const int*)d_in[1];
    const int*   bvec= (const int*)d_in[2];
    const float* W1  = (const float*)d_in[3];
    const float* b1  = (const float*)d_in[4];
    const float* W2  = (const float*)d_in[5];
    const float* b2  = (const float*)d_in[6];
    const float* W3  = (const float*)d_in[7];
    const float* b3  = (const float*)d_in[8];
    const float* W4  = (const float*)d_in[9];
    const float* b4  = (const float*)d_in[10];
    float* out = (float*)d_out;

    const int* src = ei;
    const int* dst = ei + N_EDGES;

    const size_t NF = (size_t)N_NODES * F;            // 12.8M elems
    ushort* T0  = (ushort*)d_ws;                       // NF bf16 (prescaled tables)
    ushort* T1  = T0 + NF;
    ushort* T2  = T1 + NF;
    ushort* G16 = T2 + NF;                             // N*16 bf16
    float*  aux = (float*)(G16 + (size_t)N_NODES * 16 + 64);
    int*    ecnt   = (int*)aux;                        // N
    float*  dinv   = aux + N_NODES;                    // N
    float*  sdeg   = aux + 2 * N_NODES;                // N
    int*    rowptr = (int*)(aux + 3 * N_NODES);        // N+1 (+pad)
    int*    cursor = (int*)(aux + 4 * N_NODES + 64);   // N
    int*    blkSum = (int*)(aux + 5 * N_NODES + 64);   // 256
    ushort* csr16  = (ushort*)(blkSum + 256);          // E ushorts
    float*  pool   = (float*)(csr16 + N_EDGES);        // 1024
    float*  cnt    = pool + NGRAPH * NCLS;             // 64
    ushort* Wp     = (ushort*)(cnt + NGRAPH);          // 3 x 65536

    const int BN = NBLK_N;                        // 196
    const int BE = (N_EDGES + 255) / 256;         // 3125
    const int BL = (N_NODES + 31) / 32;           // 1563 fused-layer blocks
    const int B4 = (N_NODES * 4 + 255) / 256;     // 782
    const int BP = (int)((NF / 8 + 255) / 256);   // 6250 prescale blocks

    // ---- CSR build + dinv/sdeg + zero-init
    k_init<<<BN, 256, 0, stream>>>(ecnt, pool, cnt);
    k_count<<<BE, 256, 0, stream>>>(dst, ecnt);
    k_scan_block<<<BN, 256, 0, stream>>>(ecnt, rowptr, blkSum, dinv, sdeg);
    k_scan_add<<<BN, 256, 0, stream>>>(blkSum, rowptr, cursor);
    k_fill_csr<<<BE, 256, 0, stream>>>(src, dst, cursor, csr16);

    // ---- weight packs + x prescale
    k_wpack3<<<96, 256, 0, stream>>>(W1, W2, W3, Wp);
    k_prescale<<<BP, 256, 0, stream>>>(x, dinv, T0);

    // ---- fused layers (gather-then-GEMM, commuted)
    k_layer<1><<<BL, 256, 0, stream>>>(T0, Wp,          b1, dinv, sdeg, rowptr, csr16, T1);
    k_layer<2><<<BL, 256, 0, stream>>>(T1, Wp + 65536,  b2, dinv, sdeg, rowptr, csr16, T2);
    k_layer<2><<<BL, 256, 0, stream>>>(T2, Wp + 131072, b3, dinv, sdeg, rowptr, csr16, T0);

    // ---- layer 4: G16 = T0 @ W4 (already prescaled); fused gather+pool
    k_gemm16<<<BN, 256, 0, stream>>>(T0, W4, G16);
    k_g16pool<<<B4, 256, 0, stream>>>(G16, b4, dinv, rowptr, csr16, bvec, pool, cnt);

    // ---- finalize
    k_final<<<4, 256, 0, stream>>>(pool, cnt, out);
}

// Round 15
// 375.091 us; speedup vs baseline: 1.1390x; 1.1390x over previous
//
#include <hip/hip_runtime.h>
#include <hip/hip_bf16.h>

#define N_NODES 50000
#define N_EDGES 800000
#define F 256
#define NGRAPH 64
#define NCLS 16
#define NBLK_N 196   // ceil(50000/256)

typedef short short8 __attribute__((ext_vector_type(8)));
typedef float f32x4 __attribute__((ext_vector_type(4)));

__device__ __forceinline__ float bf2f(ushort u) {
    unsigned v = ((unsigned)u) << 16;
    return __uint_as_float(v);
}
__device__ __forceinline__ ushort f2bf(float f) {
    __hip_bfloat16 b = __float2bfloat16(f);   // RNE
    return *reinterpret_cast<ushort*>(&b);
}
__device__ __forceinline__ float bflo(uint u) { return __uint_as_float(u << 16); }
__device__ __forceinline__ float bfhi(uint u) { return __uint_as_float(u & 0xffff0000u); }

// ---------------- init (zeroed buffers, fused) ----------------

__global__ __launch_bounds__(256) void k_init(int* __restrict__ ecnt,
                                              float* __restrict__ pool,
                                              float* __restrict__ cnt) {
    int i = blockIdx.x * 256 + threadIdx.x;
    if (i < N_NODES) ecnt[i] = 0;
    if (i < NGRAPH * NCLS) pool[i] = 0.f;
    if (i < NGRAPH) cnt[i] = 0.f;
}

__global__ __launch_bounds__(256) void k_count(const int* __restrict__ dst,
                                               int* __restrict__ ecnt) {
    int e = blockIdx.x * 256 + threadIdx.x;
    if (e < N_EDGES) atomicAdd(&ecnt[dst[e]], 1);
}

// block-scan over ecnt; also emits dinv and sdeg (fused)
__global__ __launch_bounds__(256) void k_scan_block(const int* __restrict__ ecnt,
                                                    int* __restrict__ rowptr,
                                                    int* __restrict__ blkSum,
                                                    float* __restrict__ dinv,
                                                    float* __restrict__ sdeg) {
    __shared__ int sh[256];
    int i = blockIdx.x * 256 + threadIdx.x;
    int v = (i < N_NODES) ? ecnt[i] : 0;
    sh[threadIdx.x] = v;
    __syncthreads();
#pragma unroll
    for (int off = 1; off < 256; off <<= 1) {
        int t = (threadIdx.x >= off) ? sh[threadIdx.x - off] : 0;
        __syncthreads();
        sh[threadIdx.x] += t;
        __syncthreads();
    }
    if (i < N_NODES) {
        rowptr[i] = sh[threadIdx.x] - v;
        float d = (float)(v + 1);
        dinv[i] = rsqrtf(d);        // +1 self-loop
        sdeg[i] = sqrtf(d);
    }
    if (threadIdx.x == 255) blkSum[blockIdx.x] = sh[255];
}

// per-block: reduce blkSum[0..bid) inline, add.
__global__ __launch_bounds__(256) void k_scan_add(const int* __restrict__ blkSum,
                                                  int* __restrict__ rowptr,
                                                  int* __restrict__ cursor) {
    __shared__ int sh[256];
    int t = threadIdx.x;
    sh[t] = (t < NBLK_N && t < (int)blockIdx.x) ? blkSum[t] : 0;
    __syncthreads();
#pragma unroll
    for (int off = 128; off > 0; off >>= 1) {
        if (t < off) sh[t] += sh[t + off];
        __syncthreads();
    }
    int base = sh[0];
    int i = blockIdx.x * 256 + t;
    if (i < N_NODES) {
        int r = rowptr[i] + base;
        rowptr[i] = r;
        cursor[i] = r;
    }
    if (i == 0) rowptr[N_NODES] = N_EDGES;
}

__global__ __launch_bounds__(256) void k_fill_csr(const int* __restrict__ src,
                                                  const int* __restrict__ dst,
                                                  int* __restrict__ cursor,
                                                  ushort* __restrict__ csr16) {
    int e = blockIdx.x * 256 + threadIdx.x;
    if (e >= N_EDGES) return;
    int s = src[e];
    int d = dst[e];
    int p = atomicAdd(&cursor[d], 1);
    csr16[p] = (ushort)s;
}

// ---------------- prescale: T0 = bf16( x * dinv[row] ) ----------------

__global__ __launch_bounds__(256) void k_prescale(const float* __restrict__ x,
                                                  const float* __restrict__ dinv,
                                                  ushort* __restrict__ T0) {
    int i = blockIdx.x * 256 + threadIdx.x;    // short8 group index
    if (i >= (int)((size_t)N_NODES * F / 8)) return;
    int n = i >> 5;                            // 32 groups per 256-row
    float di = dinv[n];
    const float4* ip = (const float4*)(x + (size_t)i * 8);
    float4 a = ip[0], b = ip[1];
    short8 v;
    v[0] = (short)f2bf(a.x * di); v[1] = (short)f2bf(a.y * di);
    v[2] = (short)f2bf(a.z * di); v[3] = (short)f2bf(a.w * di);
    v[4] = (short)f2bf(b.x * di); v[5] = (short)f2bf(b.y * di);
    v[6] = (short)f2bf(b.z * di); v[7] = (short)f2bf(b.w * di);
    *(short8*)(T0 + (size_t)i * 8) = v;
}

// ---------------- weight pack: all three 256x256 in one launch ----------------

__global__ __launch_bounds__(256) void k_wpack3(const float* __restrict__ W1,
                                                const float* __restrict__ W2,
                                                const float* __restrict__ W3,
                                                ushort* __restrict__ Wp) {
    int gid = blockIdx.x * 256 + threadIdx.x;
    int which = gid >> 13;          // 8192 frag-groups per matrix
    int idx = gid & 8191;
    const float* W = (which == 0) ? W1 : (which == 1) ? W2 : W3;
    ushort* o = Wp + (size_t)which * 65536;
    int lane = idx & 63;
    int ks = (idx >> 6) & 7;
    int ctg = idx >> 9;
    int kbase = ks * 32 + (lane >> 4) * 8;
    int col = ctg * 16 + (lane & 15);
    short8 v;
#pragma unroll
    for (int e = 0; e < 8; ++e)
        v[e] = (short)f2bf(W[(size_t)(kbase + e) * 256 + col]);
    *(short8*)(o + (size_t)idx * 8) = v;
}

// ---------------- fused layer: OUT = dinv * act( (A_hat Hs_unscaled) W + b ) ----------
// BM=16 nodes/block -> 3125 blocks, 12500 gather-waves (standalone-gather MLP),
// ~17.5 KB LDS -> ~8 blocks/CU. Phase B = single 16-row msub per wave.
// MODE 1: relu(z+b)   MODE 2: relu(relu(z+b) + prev_unscaled)

template <int MODE>
__global__ __launch_bounds__(256) void k_layer(const ushort* __restrict__ Hs,
                                               const ushort* __restrict__ Wp,
                                               const float* __restrict__ bias,
                                               const float* __restrict__ dinv,
                                               const float* __restrict__ sdeg,
                                               const int* __restrict__ rowptr,
                                               const ushort* __restrict__ csr16,
                                               ushort* __restrict__ OUT) {
    __shared__ __align__(16) ushort At[16 * 264];     // agg A-tile, padded
    __shared__ __align__(16) ushort cs[4][16 * 72];   // per-wave C stage
    const int t = threadIdx.x;
    const int wv = t >> 6;
    const int l = t & 63;
    const int m0 = blockIdx.x * 16;

    // ---- Phase A: each wave gathers 4 nodes (2-slot: 32 lanes x 16B per row) ----
    {
        const int slot = l >> 5;
        const int c = (l & 31) * 8;
#pragma unroll
        for (int rep = 0; rep < 4; ++rep) {
            const int noderow = wv * 4 + rep;
            const int n = m0 + noderow;
            const bool valid = n < N_NODES;
            const int nn = valid ? n : 0;

            float acc[8];
#pragma unroll
            for (int j = 0; j < 8; ++j) acc[j] = 0.f;

            int i = valid ? rowptr[nn] + slot : 0;
            const int end = valid ? rowptr[nn + 1] : 0;
            for (; i + 6 < end; i += 8) {
                int s0 = csr16[i], s1 = csr16[i + 2], s2 = csr16[i + 4], s3 = csr16[i + 6];
                short8 v0 = *(const short8*)(Hs + (size_t)s0 * F + c);
                short8 v1 = *(const short8*)(Hs + (size_t)s1 * F + c);
                short8 v2 = *(const short8*)(Hs + (size_t)s2 * F + c);
                short8 v3 = *(const short8*)(Hs + (size_t)s3 * F + c);
#pragma unroll
                for (int j = 0; j < 8; ++j)
                    acc[j] += (bf2f((ushort)v0[j]) + bf2f((ushort)v1[j])) +
                              (bf2f((ushort)v2[j]) + bf2f((ushort)v3[j]));
            }
            for (; i < end; i += 2) {
                int s0 = csr16[i];
                short8 v0 = *(const short8*)(Hs + (size_t)s0 * F + c);
#pragma unroll
                for (int j = 0; j < 8; ++j) acc[j] += bf2f((ushort)v0[j]);
            }

#pragma unroll
            for (int j = 0; j < 8; ++j) acc[j] += __shfl_xor(acc[j], 32);

            if (slot == 0) {
                short8 av;
                if (valid) {
                    const short8 h = *(const short8*)(Hs + (size_t)nn * F + c);
                    float di = dinv[nn];
#pragma unroll
                    for (int j = 0; j < 8; ++j)
                        av[j] = (short)f2bf(di * (acc[j] + bf2f((ushort)h[j])));
                } else {
#pragma unroll
                    for (int j = 0; j < 8; ++j) av[j] = 0;
                }
                *(short8*)&At[noderow * 264 + c] = av;
            }
        }
    }
    __syncthreads();

    // ---- Phase B+C: MFMA on A-tile (single 16-row msub), epilogue, store ----
    const int colbase = wv * 64;
    const int lrow = l & 15;
    const int lk = (l >> 4) * 8;
    const short8* wp = (const short8*)Wp;

    short8 af[8];
#pragma unroll
    for (int ks = 0; ks < 8; ++ks)
        af[ks] = *(const short8*)&At[lrow * 264 + lk + ks * 32];

#pragma unroll
    for (int ct = 0; ct < 4; ++ct) {
        short8 wf[8];
#pragma unroll
        for (int ks = 0; ks < 8; ++ks)
            wf[ks] = wp[(size_t)(((wv * 4 + ct) * 8 + ks) * 64) + l];

        f32x4 acc = (f32x4){0.f, 0.f, 0.f, 0.f};
#pragma unroll
        for (int ks = 0; ks < 8; ++ks)
            acc = __builtin_amdgcn_mfma_f32_16x16x32_bf16(af[ks], wf[ks], acc, 0, 0, 0);

        int col = ct * 16 + (l & 15);
#pragma unroll
        for (int r = 0; r < 4; ++r) {
            int row = (l >> 4) * 4 + r;
            cs[wv][row * 72 + col] = f2bf(acc[r]);
        }
    }
    // readback + epilogue: 64 lanes cover 16 rows x 64 cols (2 passes)
#pragma unroll
    for (int h = 0; h < 2; ++h) {
        int row = h * 8 + (l >> 3);
        int coff = (l & 7) * 8;
        int orow = m0 + row;
        if (orow < N_NODES) {
            short8 z8 = *(const short8*)&cs[wv][row * 72 + coff];
            int gcol = colbase + coff;
            const float4 b0 = *(const float4*)(bias + gcol);
            const float4 b1 = *(const float4*)(bias + gcol + 4);
            float bb[8] = {b0.x, b0.y, b0.z, b0.w, b1.x, b1.y, b1.z, b1.w};
            float di = dinv[orow];
            short8 ov;
            if (MODE == 2) {
                const short8 hp = *(const short8*)(Hs + (size_t)orow * F + gcol);
                float sd = sdeg[orow];
#pragma unroll
                for (int j = 0; j < 8; ++j) {
                    float u = fmaxf(bf2f((ushort)z8[j]) + bb[j], 0.f);
                    u = fmaxf(u + bf2f((ushort)hp[j]) * sd, 0.f);
                    ov[j] = (short)f2bf(u * di);
                }
            } else {
#pragma unroll
                for (int j = 0; j < 8; ++j) {
                    float u = fmaxf(bf2f((ushort)z8[j]) + bb[j], 0.f);
                    ov[j] = (short)f2bf(u * di);
                }
            }
            *(short8*)(OUT + (size_t)orow * F + gcol) = ov;
        }
    }
}

// ---------------- layer 4: GEMM 256 -> 16 on PRESCALED table ----------------

__global__ __launch_bounds__(256) void k_gemm16(const ushort* __restrict__ A,
                                                const float* __restrict__ W4,
                                                ushort* __restrict__ C) {
    __shared__ float Ws[256][16];
    const int t = threadIdx.x;
    {
        const float4* wp = (const float4*)(W4 + (size_t)t * 16);
        float4 a = wp[0], b = wp[1], c = wp[2], d = wp[3];
        float4* sp = (float4*)&Ws[t][0];
        sp[0] = a; sp[1] = b; sp[2] = c; sp[3] = d;
    }
    __syncthreads();
    int row = blockIdx.x * 256 + t;
    if (row >= N_NODES) return;
    const short8* ap = (const short8*)(A + (size_t)row * F);
    float acc[16];
#pragma unroll
    for (int c = 0; c < 16; ++c) acc[c] = 0.f;
    for (int k8 = 0; k8 < 32; ++k8) {
        short8 a8 = ap[k8];
#pragma unroll
        for (int j = 0; j < 8; ++j) {
            float av = bf2f((ushort)a8[j]);
            const float4* wr = (const float4*)&Ws[k8 * 8 + j][0];
            float4 w0 = wr[0], w1 = wr[1], w2 = wr[2], w3 = wr[3];
            acc[0]  += av * w0.x; acc[1]  += av * w0.y;
            acc[2]  += av * w0.z; acc[3]  += av * w0.w;
            acc[4]  += av * w1.x; acc[5]  += av * w1.y;
            acc[6]  += av * w1.z; acc[7]  += av * w1.w;
            acc[8]  += av * w2.x; acc[9]  += av * w2.y;
            acc[10] += av * w2.z; acc[11] += av * w2.w;
            acc[12] += av * w3.x; acc[13] += av * w3.y;
            acc[14] += av * w3.z; acc[15] += av * w3.w;
        }
    }
    short8 o0, o1;
#pragma unroll
    for (int c = 0; c < 8; ++c) o0[c] = (short)f2bf(acc[c]);
#pragma unroll
    for (int c = 0; c < 8; ++c) o1[c] = (short)f2bf(acc[8 + c]);
    short8* op = (short8*)(C + (size_t)row * 16);
    op[0] = o0; op[1] = o1;
}

// ---------------- fused layer-4 gather + mean-pool accumulate ----------------

__global__ __launch_bounds__(256) void k_g16pool(const ushort* __restrict__ G16,
                                                 const float* __restrict__ bias,
                                                 const float* __restrict__ dinv,
                                                 const int* __restrict__ rowptr,
                                                 const ushort* __restrict__ csr16,
                                                 const int* __restrict__ batch,
                                                 float* __restrict__ pool,
                                                 float* __restrict__ cnt) {
    __shared__ float ps[NGRAPH][NCLS];
    __shared__ float pc[NGRAPH];
    for (int i = threadIdx.x; i < NGRAPH * NCLS; i += 256) ((float*)ps)[i] = 0.f;
    if (threadIdx.x < NGRAPH) pc[threadIdx.x] = 0.f;
    __syncthreads();

    int gid = blockIdx.x * 256 + threadIdx.x;
    int n = gid >> 2;
    int q = (gid & 3) * 4;
    if (n < N_NODES) {
        float ax = 0.f, ay = 0.f, az = 0.f, aw = 0.f;
        const int end = rowptr[n + 1];
        for (int i = rowptr[n]; i < end; ++i) {
            int s0 = csr16[i];
            const uint2 u = *(const uint2*)(G16 + (size_t)s0 * 16 + q);
            ax += bflo(u.x); ay += bfhi(u.x);
            az += bflo(u.y); aw += bfhi(u.y);
        }
        const uint2 hu = *(const uint2*)(G16 + (size_t)n * 16 + q);
        const float4 b = *(const float4*)(bias + q);
        float di = dinv[n];
        int g = batch[n];
        atomicAdd(&ps[g][q + 0], b.x + di * (ax + bflo(hu.x)));
        atomicAdd(&ps[g][q + 1], b.y + di * (ay + bfhi(hu.x)));
        atomicAdd(&ps[g][q + 2], b.z + di * (az + bflo(hu.y)));
        atomicAdd(&ps[g][q + 3], b.w + di * (aw + bfhi(hu.y)));
        if ((gid & 3) == 0) atomicAdd(&pc[g], 1.f);
    }
    __syncthreads();

    for (int i = threadIdx.x; i < NGRAPH * NCLS; i += 256) {
        float v = ((float*)ps)[i];
        if (v != 0.f) unsafeAtomicAdd(&pool[i], v);
    }
    if (threadIdx.x < NGRAPH) {
        float v = pc[threadIdx.x];
        if (v > 0.f) unsafeAtomicAdd(&cnt[threadIdx.x], v);
    }
}

__global__ __launch_bounds__(256) void k_final(const float* __restrict__ pool,
                                               const float* __restrict__ cnt,
                                               float* __restrict__ out) {
    int i = blockIdx.x * 256 + threadIdx.x;
    if (i < NGRAPH * NCLS) out[i] = pool[i] / fmaxf(cnt[i >> 4], 1.f);
}

// ---------------- host ----------------

extern "C" void kernel_launch(void* const* d_in, const int* in_sizes, int n_in,
                              void* d_out, int out_size, void* d_ws, size_t ws_size,
                              hipStream_t stream) {
    const float* x   = (const float*)d_in[0];
    const int*   ei  = (const int*)d_in[1];
    const int*   bvec= (const int*)d_in[2];
    const float* W1  = (const float*)d_in[3];
    const float* b1  = (const float*)d_in[4];
    const float* W2  = (const float*)d_in[5];
    const float* b2  = (const float*)d_in[6];
    const float* W3  = (const float*)d_in[7];
    const float* b3  = (const float*)d_in[8];
    const float* W4  = (const float*)d_in[9];
    const float* b4  = (const float*)d_in[10];
    float* out = (float*)d_out;

    const int* src = ei;
    const int* dst = ei + N_EDGES;

    const size_t NF = (size_t)N_NODES * F;            // 12.8M elems
    ushort* T0  = (ushort*)d_ws;                       // NF bf16 (prescaled tables)
    ushort* T1  = T0 + NF;
    ushort* T2  = T1 + NF;
    ushort* G16 = T2 + NF;                             // N*16 bf16
    float*  aux = (float*)(G16 + (size_t)N_NODES * 16 + 64);
    int*    ecnt   = (int*)aux;                        // N
    float*  dinv   = aux + N_NODES;                    // N
    float*  sdeg   = aux + 2 * N_NODES;                // N
    int*    rowptr = (int*)(aux + 3 * N_NODES);        // N+1 (+pad)
    int*    cursor = (int*)(aux + 4 * N_NODES + 64);   // N
    int*    blkSum = (int*)(aux + 5 * N_NODES + 64);   // 256
    ushort* csr16  = (ushort*)(blkSum + 256);          // E ushorts
    float*  pool   = (float*)(csr16 + N_EDGES);        // 1024
    float*  cnt    = pool + NGRAPH * NCLS;             // 64
    ushort* Wp     = (ushort*)(cnt + NGRAPH);          // 3 x 65536

    const int BN = NBLK_N;                        // 196
    const int BE = (N_EDGES + 255) / 256;         // 3125
    const int BL = (N_NODES + 15) / 16;           // 3125 fused-layer blocks (BM=16)
    const int B4 = (N_NODES * 4 + 255) / 256;     // 782
    const int BP = (int)((NF / 8 + 255) / 256);   // 6250 prescale blocks

    // ---- CSR build + dinv/sdeg + zero-init
    k_init<<<BN, 256, 0, stream>>>(ecnt, pool, cnt);
    k_count<<<BE, 256, 0, stream>>>(dst, ecnt);
    k_scan_block<<<BN, 256, 0, stream>>>(ecnt, rowptr, blkSum, dinv, sdeg);
    k_scan_add<<<BN, 256, 0, stream>>>(blkSum, rowptr, cursor);
    k_fill_csr<<<BE, 256, 0, stream>>>(src, dst, cursor, csr16);

    // ---- weight packs + x prescale
    k_wpack3<<<96, 256, 0, stream>>>(W1, W2, W3, Wp);
    k_prescale<<<BP, 256, 0, stream>>>(x, dinv, T0);

    // ---- fused layers (gather-then-GEMM, commuted)
    k_layer<1><<<BL, 256, 0, stream>>>(T0, Wp,          b1, dinv, sdeg, rowptr, csr16, T1);
    k_layer<2><<<BL, 256, 0, stream>>>(T1, Wp + 65536,  b2, dinv, sdeg, rowptr, csr16, T2);
    k_layer<2><<<BL, 256, 0, stream>>>(T2, Wp + 131072, b3, dinv, sdeg, rowptr, csr16, T0);

    // ---- layer 4: G16 = T0 @ W4 (already prescaled); fused gather+pool
    k_gemm16<<<BN, 256, 0, stream>>>(T0, W4, G16);
    k_g16pool<<<B4, 256, 0, stream>>>(G16, b4, dinv, rowptr, csr16, bvec, pool, cnt);

    // ---- finalize
    k_final<<<4, 256, 0, stream>>>(pool, cnt, out);
}

// Round 16
// 350.436 us; speedup vs baseline: 1.2191x; 1.0704x over previous
//
#include <hip/hip_runtime.h>
#include <hip/hip_bf16.h>

#define N_NODES 50000
#define N_EDGES 800000
#define F 256
#define NGRAPH 64
#define NCLS 16
#define NBLK_N 196   // ceil(50000/256)

typedef short short8 __attribute__((ext_vector_type(8)));
typedef float f32x4 __attribute__((ext_vector_type(4)));

__device__ __forceinline__ float bf2f(ushort u) {
    unsigned v = ((unsigned)u) << 16;
    return __uint_as_float(v);
}
__device__ __forceinline__ ushort f2bf(float f) {
    __hip_bfloat16 b = __float2bfloat16(f);   // RNE
    return *reinterpret_cast<ushort*>(&b);
}
__device__ __forceinline__ float bflo(uint u) { return __uint_as_float(u << 16); }
__device__ __forceinline__ float bfhi(uint u) { return __uint_as_float(u & 0xffff0000u); }

// ---------------- init (zeroed buffers, fused) ----------------

__global__ __launch_bounds__(256) void k_init(int* __restrict__ ecnt,
                                              float* __restrict__ pool,
                                              float* __restrict__ cnt) {
    int i = blockIdx.x * 256 + threadIdx.x;
    if (i < N_NODES) ecnt[i] = 0;
    if (i < NGRAPH * NCLS) pool[i] = 0.f;
    if (i < NGRAPH) cnt[i] = 0.f;
}

__global__ __launch_bounds__(256) void k_count(const int* __restrict__ dst,
                                               int* __restrict__ ecnt) {
    int e = blockIdx.x * 256 + threadIdx.x;
    if (e < N_EDGES) atomicAdd(&ecnt[dst[e]], 1);
}

// block-scan over ecnt; also emits dinv and sdeg (fused)
__global__ __launch_bounds__(256) void k_scan_block(const int* __restrict__ ecnt,
                                                    int* __restrict__ rowptr,
                                                    int* __restrict__ blkSum,
                                                    float* __restrict__ dinv,
                                                    float* __restrict__ sdeg) {
    __shared__ int sh[256];
    int i = blockIdx.x * 256 + threadIdx.x;
    int v = (i < N_NODES) ? ecnt[i] : 0;
    sh[threadIdx.x] = v;
    __syncthreads();
#pragma unroll
    for (int off = 1; off < 256; off <<= 1) {
        int t = (threadIdx.x >= off) ? sh[threadIdx.x - off] : 0;
        __syncthreads();
        sh[threadIdx.x] += t;
        __syncthreads();
    }
    if (i < N_NODES) {
        rowptr[i] = sh[threadIdx.x] - v;
        float d = (float)(v + 1);
        dinv[i] = rsqrtf(d);        // +1 self-loop
        sdeg[i] = sqrtf(d);
    }
    if (threadIdx.x == 255) blkSum[blockIdx.x] = sh[255];
}

// per-block: reduce blkSum[0..bid) inline, add.
__global__ __launch_bounds__(256) void k_scan_add(const int* __restrict__ blkSum,
                                                  int* __restrict__ rowptr,
                                                  int* __restrict__ cursor) {
    __shared__ int sh[256];
    int t = threadIdx.x;
    sh[t] = (t < NBLK_N && t < (int)blockIdx.x) ? blkSum[t] : 0;
    __syncthreads();
#pragma unroll
    for (int off = 128; off > 0; off >>= 1) {
        if (t < off) sh[t] += sh[t + off];
        __syncthreads();
    }
    int base = sh[0];
    int i = blockIdx.x * 256 + t;
    if (i < N_NODES) {
        int r = rowptr[i] + base;
        rowptr[i] = r;
        cursor[i] = r;
    }
    if (i == 0) rowptr[N_NODES] = N_EDGES;
}

__global__ __launch_bounds__(256) void k_fill_csr(const int* __restrict__ src,
                                                  const int* __restrict__ dst,
                                                  int* __restrict__ cursor,
                                                  ushort* __restrict__ csr16) {
    int e = blockIdx.x * 256 + threadIdx.x;
    if (e >= N_EDGES) return;
    int s = src[e];
    int d = dst[e];
    int p = atomicAdd(&cursor[d], 1);
    csr16[p] = (ushort)s;
}

// ---------------- prescale: T0 = bf16( x * dinv[row] ) ----------------

__global__ __launch_bounds__(256) void k_prescale(const float* __restrict__ x,
                                                  const float* __restrict__ dinv,
                                                  ushort* __restrict__ T0) {
    int i = blockIdx.x * 256 + threadIdx.x;    // short8 group index
    if (i >= (int)((size_t)N_NODES * F / 8)) return;
    int n = i >> 5;                            // 32 groups per 256-row
    float di = dinv[n];
    const float4* ip = (const float4*)(x + (size_t)i * 8);
    float4 a = ip[0], b = ip[1];
    short8 v;
    v[0] = (short)f2bf(a.x * di); v[1] = (short)f2bf(a.y * di);
    v[2] = (short)f2bf(a.z * di); v[3] = (short)f2bf(a.w * di);
    v[4] = (short)f2bf(b.x * di); v[5] = (short)f2bf(b.y * di);
    v[6] = (short)f2bf(b.z * di); v[7] = (short)f2bf(b.w * di);
    *(short8*)(T0 + (size_t)i * 8) = v;
}

// ---------------- weight pack: W1..W3 (256x256) + W4 (256x16), one launch ----------------
// Wp[((ctg*8+ks)*64 + lane)*8 + e] = W[ks*32 + (lane>>4)*8 + e][ctg*16 + (lane&15)]

__global__ __launch_bounds__(256) void k_wpack(const float* __restrict__ W1,
                                               const float* __restrict__ W2,
                                               const float* __restrict__ W3,
                                               const float* __restrict__ W4,
                                               ushort* __restrict__ Wp,
                                               ushort* __restrict__ Wp4) {
    int gid = blockIdx.x * 256 + threadIdx.x;
    if (gid < 24576) {
        int which = gid >> 13;          // 8192 frag-groups per matrix
        int idx = gid & 8191;
        const float* W = (which == 0) ? W1 : (which == 1) ? W2 : W3;
        ushort* o = Wp + (size_t)which * 65536;
        int lane = idx & 63;
        int ks = (idx >> 6) & 7;
        int ctg = idx >> 9;
        int kbase = ks * 32 + (lane >> 4) * 8;
        int col = ctg * 16 + (lane & 15);
        short8 v;
#pragma unroll
        for (int e = 0; e < 8; ++e)
            v[e] = (short)f2bf(W[(size_t)(kbase + e) * 256 + col]);
        *(short8*)(o + (size_t)idx * 8) = v;
    } else if (gid < 24576 + 512) {
        int idx = gid - 24576;          // 512 groups (8 ks x 64 lanes)
        int lane = idx & 63;
        int ks = idx >> 6;
        int kbase = ks * 32 + (lane >> 4) * 8;
        int col = lane & 15;
        short8 v;
#pragma unroll
        for (int e = 0; e < 8; ++e)
            v[e] = (short)f2bf(W4[(size_t)(kbase + e) * 16 + col]);
        *(short8*)(Wp4 + (size_t)idx * 8) = v;
    }
}

// ---------------- fused layer: OUT = dinv * act( (A_hat Hs_unscaled) W + b ) ----------
// BM=16 nodes/block, 3125 blocks. Phase A: gather -> LDS A-tile. Phase B: MFMA.
// MODE 1: relu(z+b)            -> OUT
// MODE 2: relu(relu(z+b)+prev) -> OUT
// MODE 3: MODE-2 epilogue kept in LDS; wave 0 computes G16 = out16 @ W4 (no OUT write)

template <int MODE>
__global__ __launch_bounds__(256) void k_layer(const ushort* __restrict__ Hs,
                                               const ushort* __restrict__ Wp,
                                               const float* __restrict__ bias,
                                               const float* __restrict__ dinv,
                                               const float* __restrict__ sdeg,
                                               const int* __restrict__ rowptr,
                                               const ushort* __restrict__ csr16,
                                               ushort* __restrict__ OUT,
                                               const ushort* __restrict__ Wp4,
                                               ushort* __restrict__ G16) {
    __shared__ __align__(16) ushort At[16 * 264];     // agg A-tile, padded
    __shared__ __align__(16) ushort cs[4][16 * 72];   // per-wave C stage
    const int t = threadIdx.x;
    const int wv = t >> 6;
    const int l = t & 63;
    const int m0 = blockIdx.x * 16;

    // ---- Phase A: each wave gathers 4 nodes (2-slot: 32 lanes x 16B per row) ----
    {
        const int slot = l >> 5;
        const int c = (l & 31) * 8;
#pragma unroll
        for (int rep = 0; rep < 4; ++rep) {
            const int noderow = wv * 4 + rep;
            const int n = m0 + noderow;
            const bool valid = n < N_NODES;
            const int nn = valid ? n : 0;

            float acc[8];
#pragma unroll
            for (int j = 0; j < 8; ++j) acc[j] = 0.f;

            int i = valid ? rowptr[nn] + slot : 0;
            const int end = valid ? rowptr[nn + 1] : 0;
            for (; i + 6 < end; i += 8) {
                int s0 = csr16[i], s1 = csr16[i + 2], s2 = csr16[i + 4], s3 = csr16[i + 6];
                short8 v0 = *(const short8*)(Hs + (size_t)s0 * F + c);
                short8 v1 = *(const short8*)(Hs + (size_t)s1 * F + c);
                short8 v2 = *(const short8*)(Hs + (size_t)s2 * F + c);
                short8 v3 = *(const short8*)(Hs + (size_t)s3 * F + c);
#pragma unroll
                for (int j = 0; j < 8; ++j)
                    acc[j] += (bf2f((ushort)v0[j]) + bf2f((ushort)v1[j])) +
                              (bf2f((ushort)v2[j]) + bf2f((ushort)v3[j]));
            }
            for (; i < end; i += 2) {
                int s0 = csr16[i];
                short8 v0 = *(const short8*)(Hs + (size_t)s0 * F + c);
#pragma unroll
                for (int j = 0; j < 8; ++j) acc[j] += bf2f((ushort)v0[j]);
            }

#pragma unroll
            for (int j = 0; j < 8; ++j) acc[j] += __shfl_xor(acc[j], 32);

            if (slot == 0) {
                short8 av;
                if (valid) {
                    const short8 h = *(const short8*)(Hs + (size_t)nn * F + c);
                    float di = dinv[nn];
#pragma unroll
                    for (int j = 0; j < 8; ++j)
                        av[j] = (short)f2bf(di * (acc[j] + bf2f((ushort)h[j])));
                } else {
#pragma unroll
                    for (int j = 0; j < 8; ++j) av[j] = 0;
                }
                *(short8*)&At[noderow * 264 + c] = av;
            }
        }
    }
    __syncthreads();

    // ---- Phase B+C: MFMA on A-tile (single 16-row msub), epilogue ----
    const int colbase = wv * 64;
    const int lrow = l & 15;
    const int lk = (l >> 4) * 8;
    const short8* wp = (const short8*)Wp;

    short8 af[8];
#pragma unroll
    for (int ks = 0; ks < 8; ++ks)
        af[ks] = *(const short8*)&At[lrow * 264 + lk + ks * 32];

#pragma unroll
    for (int ct = 0; ct < 4; ++ct) {
        short8 wf[8];
#pragma unroll
        for (int ks = 0; ks < 8; ++ks)
            wf[ks] = wp[(size_t)(((wv * 4 + ct) * 8 + ks) * 64) + l];

        f32x4 acc = (f32x4){0.f, 0.f, 0.f, 0.f};
#pragma unroll
        for (int ks = 0; ks < 8; ++ks)
            acc = __builtin_amdgcn_mfma_f32_16x16x32_bf16(af[ks], wf[ks], acc, 0, 0, 0);

        int col = ct * 16 + (l & 15);
#pragma unroll
        for (int r = 0; r < 4; ++r) {
            int row = (l >> 4) * 4 + r;
            cs[wv][row * 72 + col] = f2bf(acc[r]);
        }
    }
    // readback + epilogue: 64 lanes cover 16 rows x 64 cols (2 passes)
#pragma unroll
    for (int h = 0; h < 2; ++h) {
        int row = h * 8 + (l >> 3);
        int coff = (l & 7) * 8;
        int orow = m0 + row;
        if (orow < N_NODES) {
            short8 z8 = *(const short8*)&cs[wv][row * 72 + coff];
            int gcol = colbase + coff;
            const float4 b0 = *(const float4*)(bias + gcol);
            const float4 b1 = *(const float4*)(bias + gcol + 4);
            float bb[8] = {b0.x, b0.y, b0.z, b0.w, b1.x, b1.y, b1.z, b1.w};
            float di = dinv[orow];
            short8 ov;
            if (MODE >= 2) {
                const short8 hp = *(const short8*)(Hs + (size_t)orow * F + gcol);
                float sd = sdeg[orow];
#pragma unroll
                for (int j = 0; j < 8; ++j) {
                    float u = fmaxf(bf2f((ushort)z8[j]) + bb[j], 0.f);
                    u = fmaxf(u + bf2f((ushort)hp[j]) * sd, 0.f);
                    ov[j] = (short)f2bf(u * di);
                }
            } else {
#pragma unroll
                for (int j = 0; j < 8; ++j) {
                    float u = fmaxf(bf2f((ushort)z8[j]) + bb[j], 0.f);
                    ov[j] = (short)f2bf(u * di);
                }
            }
            if (MODE == 3) {
                *(short8*)&cs[wv][row * 72 + coff] = ov;   // keep in LDS for W4 MFMA
            } else {
                *(short8*)(OUT + (size_t)orow * F + gcol) = ov;
            }
        } else if (MODE == 3) {
            short8 zv;
#pragma unroll
            for (int j = 0; j < 8; ++j) zv[j] = 0;
            *(short8*)&cs[wv][row * 72 + coff] = zv;
        }
    }

    if (MODE == 3) {
        __syncthreads();
        if (wv == 0) {
            // G16[m0+row][0:16] = out16 @ W4  (out16 = post-epilogue, prescaled)
            const short8* wp4 = (const short8*)Wp4;
            f32x4 acc = (f32x4){0.f, 0.f, 0.f, 0.f};
#pragma unroll
            for (int ks = 0; ks < 8; ++ks) {
                int cbase = lk + ks * 32;               // global col of 8-run
                short8 a2 = *(const short8*)&cs[cbase >> 6][lrow * 72 + (cbase & 63)];
                short8 w4 = wp4[(size_t)(ks * 64) + l];
                acc = __builtin_amdgcn_mfma_f32_16x16x32_bf16(a2, w4, acc, 0, 0, 0);
            }
            int col = l & 15;
#pragma unroll
            for (int r = 0; r < 4; ++r) {
                int row = (l >> 4) * 4 + r;
                int orow = m0 + row;
                if (orow < N_NODES)
                    G16[(size_t)orow * 16 + col] = f2bf(acc[r]);
            }
        }
    }
}

// ---------------- fused layer-4 gather + mean-pool accumulate ----------------

__global__ __launch_bounds__(256) void k_g16pool(const ushort* __restrict__ G16,
                                                 const float* __restrict__ bias,
                                                 const float* __restrict__ dinv,
                                                 const int* __restrict__ rowptr,
                                                 const ushort* __restrict__ csr16,
                                                 const int* __restrict__ batch,
                                                 float* __restrict__ pool,
                                                 float* __restrict__ cnt) {
    __shared__ float ps[NGRAPH][NCLS];
    __shared__ float pc[NGRAPH];
    for (int i = threadIdx.x; i < NGRAPH * NCLS; i += 256) ((float*)ps)[i] = 0.f;
    if (threadIdx.x < NGRAPH) pc[threadIdx.x] = 0.f;
    __syncthreads();

    int gid = blockIdx.x * 256 + threadIdx.x;
    int n = gid >> 2;
    int q = (gid & 3) * 4;
    if (n < N_NODES) {
        float ax = 0.f, ay = 0.f, az = 0.f, aw = 0.f;
        const int end = rowptr[n + 1];
        for (int i = rowptr[n]; i < end; ++i) {
            int s0 = csr16[i];
            const uint2 u = *(const uint2*)(G16 + (size_t)s0 * 16 + q);
            ax += bflo(u.x); ay += bfhi(u.x);
            az += bflo(u.y); aw += bfhi(u.y);
        }
        const uint2 hu = *(const uint2*)(G16 + (size_t)n * 16 + q);
        const float4 b = *(const float4*)(bias + q);
        float di = dinv[n];
        int g = batch[n];
        atomicAdd(&ps[g][q + 0], b.x + di * (ax + bflo(hu.x)));
        atomicAdd(&ps[g][q + 1], b.y + di * (ay + bfhi(hu.x)));
        atomicAdd(&ps[g][q + 2], b.z + di * (az + bflo(hu.y)));
        atomicAdd(&ps[g][q + 3], b.w + di * (aw + bfhi(hu.y)));
        if ((gid & 3) == 0) atomicAdd(&pc[g], 1.f);
    }
    __syncthreads();

    for (int i = threadIdx.x; i < NGRAPH * NCLS; i += 256) {
        float v = ((float*)ps)[i];
        if (v != 0.f) unsafeAtomicAdd(&pool[i], v);
    }
    if (threadIdx.x < NGRAPH) {
        float v = pc[threadIdx.x];
        if (v > 0.f) unsafeAtomicAdd(&cnt[threadIdx.x], v);
    }
}

__global__ __launch_bounds__(256) void k_final(const float* __restrict__ pool,
                                               const float* __restrict__ cnt,
                                               float* __restrict__ out) {
    int i = blockIdx.x * 256 + threadIdx.x;
    if (i < NGRAPH * NCLS) out[i] = pool[i] / fmaxf(cnt[i >> 4], 1.f);
}

// ---------------- host ----------------

extern "C" void kernel_launch(void* const* d_in, const int* in_sizes, int n_in,
                              void* d_out, int out_size, void* d_ws, size_t ws_size,
                              hipStream_t stream) {
    const float* x   = (const float*)d_in[0];
    const int*   ei  = (const int*)d_in[1];
    const int*   bvec= (const int*)d_in[2];
    const float* W1  = (const float*)d_in[3];
    const float* b1  = (const float*)d_in[4];
    const float* W2  = (const float*)d_in[5];
    const float* b2  = (const float*)d_in[6];
    const float* W3  = (const float*)d_in[7];
    const float* b3  = (const float*)d_in[8];
    const float* W4  = (const float*)d_in[9];
    const float* b4  = (const float*)d_in[10];
    float* out = (float*)d_out;

    const int* src = ei;
    const int* dst = ei + N_EDGES;

    const size_t NF = (size_t)N_NODES * F;            // 12.8M elems
    ushort* T0  = (ushort*)d_ws;                       // NF bf16 (prescaled tables)
    ushort* T1  = T0 + NF;
    ushort* T2  = T1 + NF;
    ushort* G16 = T2 + NF;                             // N*16 bf16
    float*  aux = (float*)(G16 + (size_t)N_NODES * 16 + 64);
    int*    ecnt   = (int*)aux;                        // N
    float*  dinv   = aux + N_NODES;                    // N
    float*  sdeg   = aux + 2 * N_NODES;                // N
    int*    rowptr = (int*)(aux + 3 * N_NODES);        // N+1 (+pad)
    int*    cursor = (int*)(aux + 4 * N_NODES + 64);   // N
    int*    blkSum = (int*)(aux + 5 * N_NODES + 64);   // 256
    ushort* csr16  = (ushort*)(blkSum + 256);          // E ushorts
    float*  pool   = (float*)(csr16 + N_EDGES);        // 1024
    float*  cnt    = pool + NGRAPH * NCLS;             // 64
    ushort* Wp     = (ushort*)(cnt + NGRAPH);          // 3 x 65536
    ushort* Wp4    = Wp + 3 * 65536;                   // 4096

    const int BN = NBLK_N;                        // 196
    const int BE = (N_EDGES + 255) / 256;         // 3125
    const int BL = (N_NODES + 15) / 16;           // 3125 fused-layer blocks (BM=16)
    const int B4 = (N_NODES * 4 + 255) / 256;     // 782
    const int BP = (int)((NF / 8 + 255) / 256);   // 6250 prescale blocks

    // ---- CSR build + dinv/sdeg + zero-init
    k_init<<<BN, 256, 0, stream>>>(ecnt, pool, cnt);
    k_count<<<BE, 256, 0, stream>>>(dst, ecnt);
    k_scan_block<<<BN, 256, 0, stream>>>(ecnt, rowptr, blkSum, dinv, sdeg);
    k_scan_add<<<BN, 256, 0, stream>>>(blkSum, rowptr, cursor);
    k_fill_csr<<<BE, 256, 0, stream>>>(src, dst, cursor, csr16);

    // ---- weight packs (W1..W4) + x prescale
    k_wpack<<<99, 256, 0, stream>>>(W1, W2, W3, W4, Wp, Wp4);
    k_prescale<<<BP, 256, 0, stream>>>(x, dinv, T0);

    // ---- fused layers (gather-then-GEMM, commuted)
    k_layer<1><<<BL, 256, 0, stream>>>(T0, Wp,          b1, dinv, sdeg, rowptr, csr16, T1, nullptr, nullptr);
    k_layer<2><<<BL, 256, 0, stream>>>(T1, Wp + 65536,  b2, dinv, sdeg, rowptr, csr16, T2, nullptr, nullptr);
    // layer 3 + layer-4 GEMM fused: emits G16 directly, no T-table write
    k_layer<3><<<BL, 256, 0, stream>>>(T2, Wp + 131072, b3, dinv, sdeg, rowptr, csr16, nullptr, Wp4, G16);

    // ---- layer 4 aggregation + mean pool
    k_g16pool<<<B4, 256, 0, stream>>>(G16, b4, dinv, rowptr, csr16, bvec, pool, cnt);

    // ---- finalize
    k_final<<<4, 256, 0, stream>>>(pool, cnt, out);
}